// Round 1
// baseline (346.376 us; speedup 1.0000x reference)
//
#include <hip/hip_runtime.h>
#include <math.h>

#define B 8
#define V 1024
#define E 32
#define F 64
#define H 4
#define HIDN 64
#define CAP 64   // max degree capacity; E[deg]=17, P(deg>64) ~ 1e-21

__device__ __forceinline__ float wave_sum(float v) {
  for (int o = 32; o > 0; o >>= 1) v += __shfl_xor(v, o);
  return v;
}
__device__ __forceinline__ float wave_max(float v) {
  for (int o = 32; o > 0; o >>= 1) v = fmaxf(v, __shfl_xor(v, o));
  return v;
}

// ---- adjacency -> CSR out-neighbor lists (deterministic ballot compaction) ----
__global__ void build_csr(const float* __restrict__ adj, int* __restrict__ nbr,
                          int* __restrict__ deg) {
  int v = blockIdx.x;
  int lane = threadIdx.x;
  int base = 0;
  for (int c = 0; c < V; c += 64) {
    float a = adj[v * V + c + lane];
    unsigned long long m = __ballot(a > 0.5f);
    int pos = __popcll(m & ((1ull << lane) - 1ull));
    if (a > 0.5f && base + pos < CAP) nbr[v * CAP + base + pos] = c + lane;
    base += __popcll(m);
  }
  if (lane == 0) deg[v] = (base < CAP) ? base : CAP;
}

// ---- adjacency -> CSC in-neighbor lists + index into fw edge array ----
__global__ void build_csc(const float* __restrict__ adj, const int* __restrict__ nbr_out,
                          const int* __restrict__ deg_out, int* __restrict__ in_src,
                          int* __restrict__ in_fwidx, int* __restrict__ deg_in) {
  int w = blockIdx.x;
  int lane = threadIdx.x;
  int base = 0;
  for (int c = 0; c < V; c += 64) {
    int v = c + lane;
    float a = adj[v * V + w];
    unsigned long long m = __ballot(a > 0.5f);
    int pos = __popcll(m & ((1ull << lane) - 1ull));
    if (a > 0.5f && base + pos < CAP) {
      int dv_ = deg_out[v];
      int kk = 0;
      for (int k = 0; k < dv_; ++k) {
        if (nbr_out[v * CAP + k] == w) { kk = k; break; }
      }
      in_src[w * CAP + base + pos] = v;
      in_fwidx[w * CAP + base + pos] = v * CAP + kk;
    }
    base += __popcll(m);
  }
  if (lane == 0) deg_in[w] = (base < CAP) ? base : CAP;
}

// ---- encoder MLP: relu(relu(x@w1+b1)@w2+b2), x = [emb, demand] ----
__global__ void enc_kernel(const float* __restrict__ demands, const float* __restrict__ emb,
                           const float* __restrict__ w1, const float* __restrict__ b1,
                           const float* __restrict__ w2, const float* __restrict__ b2,
                           float* __restrict__ enc) {
  int bv = blockIdx.x;
  int b = bv >> 10, v = bv & 1023;
  int j = threadIdx.x;  // 64
  __shared__ float xs[E + 1];
  __shared__ float hs[HIDN];
  if (j < E) xs[j] = emb[v * E + j];
  else if (j == E) xs[E] = demands[b * V + v];
  __syncthreads();
  float h = b1[j];
#pragma unroll
  for (int i = 0; i < E + 1; ++i) h += xs[i] * w1[i * 64 + j];
  hs[j] = fmaxf(h, 0.f);
  __syncthreads();
  float o = b2[j];
#pragma unroll
  for (int i = 0; i < 64; ++i) o += hs[i] * w2[i * 64 + j];
  enc[bv * 64 + j] = fmaxf(o, 0.f);
}

// ---- t = einsum('bvf,hfg->bhvg'), s_self/s_nbr projections ----
__global__ void t_kernel(const float* __restrict__ enc, const float* __restrict__ gat_w,
                         const float* __restrict__ a1, const float* __restrict__ a2,
                         float* __restrict__ t, float* __restrict__ s_self,
                         float* __restrict__ s_nbr) {
  int bv = blockIdx.x;
  int b = bv >> 10, v = bv & 1023;
  int tid = threadIdx.x;
  int h = tid >> 6, g = tid & 63;
  __shared__ float es[64];
  if (tid < 64) es[tid] = enc[bv * 64 + tid];
  __syncthreads();
  const float* w = gat_w + h * 64 * 64 + g;
  float acc = 0.f;
#pragma unroll
  for (int f = 0; f < 64; ++f) acc += es[f] * w[f * 64];
  t[((size_t)(b * H + h) * V + v) * 64 + g] = acc;
  float v1 = wave_sum(acc * a1[h * 64 + g]);
  float v2 = wave_sum(acc * a2[h * 64 + g]);
  if (g == 0) {
    s_self[(b * H + h) * V + v] = v1;
    s_nbr[(b * H + h) * V + v] = v2;
  }
}

// ---- sparse GAT attention + head-mean + GRU-style gate ----
__global__ void gat_kernel(const float* __restrict__ enc_in, const float* __restrict__ t,
                           const float* __restrict__ s_self, const float* __restrict__ s_nbr,
                           const int* __restrict__ nbr, const int* __restrict__ deg,
                           const float* __restrict__ gate_w, const float* __restrict__ gate_u,
                           const float* __restrict__ gate_b, float* __restrict__ enc_out) {
  int bv = blockIdx.x;
  int b = bv >> 10, v = bv & 1023;
  int tid = threadIdx.x;
  int h = tid >> 6, lane = tid & 63;
  int dvv = deg[v];
  int wk = (lane < dvv) ? nbr[v * CAP + lane] : 0;
  float logit = -1e30f;
  if (lane < dvv) {
    float x = s_self[(b * H + h) * V + v] + s_nbr[(b * H + h) * V + wk];
    logit = (x > 0.f) ? x : 0.2f * x;  // leaky_relu 0.2
  }
  float m = wave_max(logit);
  float e = (lane < dvv) ? __expf(logit - m) : 0.f;
  float s = wave_sum(e);
  float coef = e / s;
  const float* tb = t + (size_t)(b * H + h) * (V * 64);
  float acc = 0.f;
  for (int k = 0; k < dvv; ++k) {
    float c = __shfl(coef, k);
    int w = __shfl(wk, k);
    acc += c * tb[w * 64 + lane];
  }
  __shared__ float hsum[4][64];
  __shared__ float nxts[64], encs[64];
  hsum[h][lane] = acc;
  __syncthreads();
  if (tid < 64) {
    float s4 = hsum[0][tid] + hsum[1][tid] + hsum[2][tid] + hsum[3][tid];
    nxts[tid] = fmaxf(0.25f * s4, 0.f);
    encs[tid] = enc_in[bv * 64 + tid];
  }
  __syncthreads();
  // gate: z = sigmoid(nxt@gate_w + enc@gate_u + gate_b); split f-range over waves
  float part = 0.f;
  for (int f = h * 16; f < h * 16 + 16; ++f)
    part += nxts[f] * gate_w[f * 64 + lane] + encs[f] * gate_u[f * 64 + lane];
  __syncthreads();
  hsum[h][lane] = part;
  __syncthreads();
  if (tid < 64) {
    float zs = hsum[0][tid] + hsum[1][tid] + hsum[2][tid] + hsum[3][tid] + gate_b[tid];
    float z = 1.f / (1.f + __expf(-zs));
    enc_out[bv * 64 + tid] = z * nxts[tid] + (1.f - z) * encs[tid];
  }
}

// ---- decoder hidden (linear) + dual variable dv (linear MLP -> scalar) ----
__global__ void dec_dual_kernel(const float* __restrict__ enc, const float* __restrict__ dw1,
                                const float* __restrict__ db1, const float* __restrict__ uw1,
                                const float* __restrict__ ub1, const float* __restrict__ uw2,
                                const float* __restrict__ ub2, float* __restrict__ hid,
                                float* __restrict__ dv) {
  int bv = blockIdx.x;
  int j = threadIdx.x;  // 64
  __shared__ float es[64];
  es[j] = enc[bv * 64 + j];
  __syncthreads();
  float hj = db1[j], uj = ub1[j];
#pragma unroll
  for (int f = 0; f < 64; ++f) {
    hj += es[f] * dw1[f * 64 + j];
    uj += es[f] * uw1[f * 64 + j];
  }
  hid[bv * 64 + j] = hj;  // NO relu: decoder is linear
  float dvs = wave_sum(uj * uw2[j]);
  if (j == 0) dv[bv] = dvs + ub2[0];
}

__global__ void transpose_w2(const float* __restrict__ w2, float* __restrict__ w2t) {
  int w = blockIdx.x, j = threadIdx.x;
  w2t[w * 64 + j] = w2[j * V + w];
}

// ---- flow weights: softmax over out-edges of pred^2; also row sum of fw^2 ----
__global__ void fw_kernel(const float* __restrict__ hid, const float* __restrict__ w2t,
                          const float* __restrict__ b2, const int* __restrict__ nbr,
                          const int* __restrict__ deg, float* __restrict__ fw,
                          float* __restrict__ rssq) {
  int bv = blockIdx.x;
  int v = bv & 1023;
  int lane = threadIdx.x;  // 64
  float hj = hid[bv * 64 + lane];
  int dvv = deg[v];
  float myp = -1e30f;
  for (int k = 0; k < dvv; ++k) {
    int w = nbr[v * CAP + k];  // wave-uniform
    float d = wave_sum(hj * w2t[w * 64 + lane]);
    float pp = d + b2[w];
    pp = pp * pp;
    if (lane == k) myp = pp;
  }
  float m = wave_max(myp);
  float e = (lane < dvv) ? __expf(myp - m) : 0.f;
  float s = wave_sum(e);
  float coef = e / s;
  fw[bv * CAP + lane] = coef;  // zero-padded beyond deg
  float r = wave_sum(coef * coef);
  if (lane == 0) rssq[bv] = r;
}

// ---- 9 sparse matvec flow iterations + flow cost + dual cost, per batch ----
__global__ void flow_dual_kernel(const float* __restrict__ fw, const float* __restrict__ rssq,
                                 const int* __restrict__ in_src, const int* __restrict__ in_fwidx,
                                 const int* __restrict__ deg_in, const float* __restrict__ dv,
                                 const float* __restrict__ demands,
                                 const int* __restrict__ nbr_out, const int* __restrict__ deg_out,
                                 float* __restrict__ partial) {
  int b = blockIdx.x;
  int v = threadIdx.x;  // 1024
  __shared__ float o[V];
  float dem = demands[b * V + v];
  o[v] = fmaxf(-dem, 0.f);  // o_1
  int din = deg_in[v];
  const float* fwb = fw + (size_t)b * V * CAP;
  __syncthreads();
  for (int it = 0; it < 9; ++it) {
    float inflow = 0.f;
    for (int p = 0; p < din; ++p)
      inflow += fwb[in_fwidx[v * CAP + p]] * o[in_src[v * CAP + p]];
    float nv = fmaxf(inflow - dem, 0.f);
    __syncthreads();
    o[v] = nv;
    __syncthreads();
  }
  float o10 = o[v];
  float local = o10 * o10 * rssq[b * V + v];  // flow_cost contribution
  // dual: loss_b = flow_cost + 0.25*sum_edges relu(dv_v - dv_w)^2 + sum_v dv_v*dem_v
  float dvv = dv[b * V + v];
  int dout = deg_out[v];
  float acc = 0.f;
  for (int k = 0; k < dout; ++k) {
    float diff = dvv - dv[b * V + nbr_out[v * CAP + k]];
    if (diff > 0.f) acc += diff * diff;
  }
  local += 0.25f * acc + dvv * dem;
  __syncthreads();
  o[v] = local;
  __syncthreads();
  for (int s = 512; s > 0; s >>= 1) {
    if (v < s) o[v] += o[v + s];
    __syncthreads();
  }
  if (v == 0) partial[b] = o[0];
}

__global__ void final_kernel(const float* __restrict__ partial, float* __restrict__ out) {
  if (threadIdx.x == 0) {
    float s = 0.f;
    for (int b = 0; b < B; ++b) s += partial[b];
    out[0] = s * (1.0f / B);
  }
}

extern "C" void kernel_launch(void* const* d_in, const int* in_sizes, int n_in,
                              void* d_out, int out_size, void* d_ws, size_t ws_size,
                              hipStream_t stream) {
  const float* demands = (const float*)d_in[0];
  const float* emb     = (const float*)d_in[1];
  const float* adj     = (const float*)d_in[2];
  const float* enc_w1  = (const float*)d_in[3];
  const float* enc_b1  = (const float*)d_in[4];
  const float* enc_w2  = (const float*)d_in[5];
  const float* enc_b2  = (const float*)d_in[6];
  const float* gat_w   = (const float*)d_in[7];
  const float* gat_a1  = (const float*)d_in[8];
  const float* gat_a2  = (const float*)d_in[9];
  const float* gate_w  = (const float*)d_in[10];
  const float* gate_u  = (const float*)d_in[11];
  const float* gate_b  = (const float*)d_in[12];
  const float* dec_w1  = (const float*)d_in[13];
  const float* dec_b1  = (const float*)d_in[14];
  const float* dec_w2  = (const float*)d_in[15];
  const float* dec_b2  = (const float*)d_in[16];
  const float* dual_w1 = (const float*)d_in[17];
  const float* dual_b1 = (const float*)d_in[18];
  const float* dual_w2 = (const float*)d_in[19];
  const float* dual_b2 = (const float*)d_in[20];

  char* p = (char*)d_ws;
  auto alloc = [&](size_t n) { void* r = (void*)p; p += n; return r; };
  int* nbr_out   = (int*)alloc((size_t)V * CAP * 4);
  int* deg_out   = (int*)alloc((size_t)V * 4);
  int* in_src    = (int*)alloc((size_t)V * CAP * 4);
  int* in_fwidx  = (int*)alloc((size_t)V * CAP * 4);
  int* deg_in    = (int*)alloc((size_t)V * 4);
  float* w2t     = (float*)alloc((size_t)HIDN * V * 4);
  float* encA    = (float*)alloc((size_t)B * V * 64 * 4);
  float* encB    = (float*)alloc((size_t)B * V * 64 * 4);
  float* t       = (float*)alloc((size_t)B * H * V * 64 * 4);
  float* s_self  = (float*)alloc((size_t)B * H * V * 4);
  float* s_nbr   = (float*)alloc((size_t)B * H * V * 4);
  float* hid     = (float*)alloc((size_t)B * V * 64 * 4);
  float* dv      = (float*)alloc((size_t)B * V * 4);
  float* fw      = (float*)alloc((size_t)B * V * CAP * 4);
  float* rssq    = (float*)alloc((size_t)B * V * 4);
  float* partial = (float*)alloc((size_t)B * 4);

  build_csr<<<V, 64, 0, stream>>>(adj, nbr_out, deg_out);
  build_csc<<<V, 64, 0, stream>>>(adj, nbr_out, deg_out, in_src, in_fwidx, deg_in);
  enc_kernel<<<B * V, 64, 0, stream>>>(demands, emb, enc_w1, enc_b1, enc_w2, enc_b2, encA);
  float* cur = encA;
  float* nxt = encB;
  for (int l = 0; l < 2; ++l) {
    t_kernel<<<B * V, 256, 0, stream>>>(cur, gat_w, gat_a1, gat_a2, t, s_self, s_nbr);
    gat_kernel<<<B * V, 256, 0, stream>>>(cur, t, s_self, s_nbr, nbr_out, deg_out,
                                          gate_w, gate_u, gate_b, nxt);
    float* tmp = cur; cur = nxt; nxt = tmp;
  }
  transpose_w2<<<V, 64, 0, stream>>>(dec_w2, w2t);
  dec_dual_kernel<<<B * V, 64, 0, stream>>>(cur, dec_w1, dec_b1, dual_w1, dual_b1,
                                            dual_w2, dual_b2, hid, dv);
  fw_kernel<<<B * V, 64, 0, stream>>>(hid, w2t, dec_b2, nbr_out, deg_out, fw, rssq);
  flow_dual_kernel<<<B, 1024, 0, stream>>>(fw, rssq, in_src, in_fwidx, deg_in, dv, demands,
                                           nbr_out, deg_out, partial);
  final_kernel<<<1, 64, 0, stream>>>(partial, (float*)d_out);
}

// Round 2
// 262.610 us; speedup vs baseline: 1.3190x; 1.3190x over previous
//
#include <hip/hip_runtime.h>
#include <math.h>

#define B 8
#define V 1024
#define E 32
#define F 64
#define H 4
#define HIDN 64
#define CAP 64      // max degree capacity; E[deg]=17, P(deg>64) ~ 1e-21
#define MAXNNZ 20480  // nnz ~ 17392 +/- 127; +24 sigma headroom

__device__ __forceinline__ float wave_sum(float v) {
  for (int o = 32; o > 0; o >>= 1) v += __shfl_xor(v, o);
  return v;
}
__device__ __forceinline__ float wave_max(float v) {
  for (int o = 32; o > 0; o >>= 1) v = fmaxf(v, __shfl_xor(v, o));
  return v;
}

// ---- adjacency -> CSR out-neighbor lists (deterministic ballot compaction) ----
__global__ void build_csr(const float* __restrict__ adj, int* __restrict__ nbr,
                          int* __restrict__ deg) {
  int v = blockIdx.x;
  int lane = threadIdx.x;
  int base = 0;
  for (int c = 0; c < V; c += 64) {
    float a = adj[v * V + c + lane];
    unsigned long long m = __ballot(a > 0.5f);
    int pos = __popcll(m & ((1ull << lane) - 1ull));
    if (a > 0.5f && base + pos < CAP) nbr[v * CAP + base + pos] = c + lane;
    base += __popcll(m);
  }
  if (lane == 0) deg[v] = (base < CAP) ? base : CAP;
}

// ---- adjacency -> CSC in-neighbor lists + index into fw edge array ----
__global__ void build_csc(const float* __restrict__ adj, const int* __restrict__ nbr_out,
                          const int* __restrict__ deg_out, int* __restrict__ in_src,
                          int* __restrict__ in_fwidx, int* __restrict__ deg_in) {
  int w = blockIdx.x;
  int lane = threadIdx.x;
  int base = 0;
  for (int c = 0; c < V; c += 64) {
    int v = c + lane;
    float a = adj[v * V + w];
    unsigned long long m = __ballot(a > 0.5f);
    int pos = __popcll(m & ((1ull << lane) - 1ull));
    if (a > 0.5f && base + pos < CAP) {
      int dv_ = deg_out[v];
      int kk = 0;
      for (int k = 0; k < dv_; ++k) {
        if (nbr_out[v * CAP + k] == w) { kk = k; break; }
      }
      in_src[w * CAP + base + pos] = v;
      in_fwidx[w * CAP + base + pos] = v * CAP + kk;
    }
    base += __popcll(m);
  }
  if (lane == 0) deg_in[w] = (base < CAP) ? base : CAP;
}

// ---- exclusive prefix scan of deg_in -> in_off[V+1], single block ----
__global__ void scan_kernel(const int* __restrict__ deg_in, int* __restrict__ in_off) {
  __shared__ int s[V];
  int v = threadIdx.x;
  int d = deg_in[v];
  s[v] = d;
  __syncthreads();
  for (int o = 1; o < V; o <<= 1) {
    int t = (v >= o) ? s[v - o] : 0;
    __syncthreads();
    s[v] += t;
    __syncthreads();
  }
  in_off[v] = s[v] - d;  // exclusive
  if (v == V - 1) in_off[V] = s[v];
}

// ---- compact padded CSC into contiguous edge arrays ----
__global__ void compact_csc(const int* __restrict__ in_src, const int* __restrict__ in_fwidx,
                            const int* __restrict__ deg_in, const int* __restrict__ in_off,
                            unsigned short* __restrict__ c_src, int* __restrict__ c_fwi) {
  int v = blockIdx.x;
  int lane = threadIdx.x;  // 64
  int d = deg_in[v], o = in_off[v];
  if (lane < d) {
    c_src[o + lane] = (unsigned short)in_src[v * CAP + lane];
    c_fwi[o + lane] = in_fwidx[v * CAP + lane];
  }
}

// ---- encoder MLP, 8 nodes/block to amortize weight reads ----
#define ENV 8
__global__ void enc_kernel(const float* __restrict__ demands, const float* __restrict__ emb,
                           const float* __restrict__ w1, const float* __restrict__ b1,
                           const float* __restrict__ w2, const float* __restrict__ b2,
                           float* __restrict__ enc) {
  int bv0 = blockIdx.x * ENV;
  int b = bv0 >> 10, v0 = bv0 & 1023;
  int j = threadIdx.x;  // 64
  __shared__ float xs[ENV][E + 1];
  __shared__ float hs[ENV][64];
#pragma unroll
  for (int n = 0; n < ENV; ++n) {
    if (j < E) xs[n][j] = emb[(v0 + n) * E + j];
    else if (j == E) xs[n][E] = demands[b * V + v0 + n];
  }
  __syncthreads();
  float h[ENV];
#pragma unroll
  for (int n = 0; n < ENV; ++n) h[n] = b1[j];
  for (int i = 0; i < E + 1; ++i) {
    float wv = w1[i * 64 + j];
#pragma unroll
    for (int n = 0; n < ENV; ++n) h[n] += xs[n][i] * wv;
  }
#pragma unroll
  for (int n = 0; n < ENV; ++n) hs[n][j] = fmaxf(h[n], 0.f);
  __syncthreads();
  float o[ENV];
#pragma unroll
  for (int n = 0; n < ENV; ++n) o[n] = b2[j];
  for (int i = 0; i < 64; ++i) {
    float wv = w2[i * 64 + j];
#pragma unroll
    for (int n = 0; n < ENV; ++n) o[n] += hs[n][i] * wv;
  }
#pragma unroll
  for (int n = 0; n < ENV; ++n) enc[(bv0 + n) * 64 + j] = fmaxf(o[n], 0.f);
}

// ---- t = einsum('bvf,hfg->bhvg') + attention score projections, 8 nodes/block ----
#define TNV 8
__global__ void t_kernel(const float* __restrict__ enc, const float* __restrict__ gat_w,
                         const float* __restrict__ a1, const float* __restrict__ a2,
                         float* __restrict__ t, float* __restrict__ s_self,
                         float* __restrict__ s_nbr) {
  int bv0 = blockIdx.x * TNV;
  int b = bv0 >> 10, v0 = bv0 & 1023;
  int tid = threadIdx.x;  // 256
  int h = tid >> 6, g = tid & 63;
  __shared__ float es[TNV][64];
  for (int i = tid; i < TNV * 64; i += 256) es[i >> 6][i & 63] = enc[bv0 * 64 + i];
  __syncthreads();
  float acc[TNV];
#pragma unroll
  for (int n = 0; n < TNV; ++n) acc[n] = 0.f;
  const float* w = gat_w + h * 64 * 64 + g;
  for (int f = 0; f < 64; ++f) {
    float wf = w[f * 64];
#pragma unroll
    for (int n = 0; n < TNV; ++n) acc[n] += es[n][f] * wf;
  }
  float a1v = a1[h * 64 + g], a2v = a2[h * 64 + g];
#pragma unroll
  for (int n = 0; n < TNV; ++n) {
    t[((size_t)(b * H + h) * V + (v0 + n)) * 64 + g] = acc[n];
    float v1 = wave_sum(acc[n] * a1v);
    float v2 = wave_sum(acc[n] * a2v);
    if (g == 0) {
      s_self[(b * H + h) * V + (v0 + n)] = v1;
      s_nbr[(b * H + h) * V + (v0 + n)] = v2;
    }
  }
}

// ---- sparse GAT attention + head-mean + GRU-style gate ----
__global__ void gat_kernel(const float* __restrict__ enc_in, const float* __restrict__ t,
                           const float* __restrict__ s_self, const float* __restrict__ s_nbr,
                           const int* __restrict__ nbr, const int* __restrict__ deg,
                           const float* __restrict__ gate_w, const float* __restrict__ gate_u,
                           const float* __restrict__ gate_b, float* __restrict__ enc_out) {
  int bv = blockIdx.x;
  int b = bv >> 10, v = bv & 1023;
  int tid = threadIdx.x;
  int h = tid >> 6, lane = tid & 63;
  int dvv = deg[v];
  int wk = (lane < dvv) ? nbr[v * CAP + lane] : 0;
  float logit = -1e30f;
  if (lane < dvv) {
    float x = s_self[(b * H + h) * V + v] + s_nbr[(b * H + h) * V + wk];
    logit = (x > 0.f) ? x : 0.2f * x;  // leaky_relu 0.2
  }
  float m = wave_max(logit);
  float e = (lane < dvv) ? __expf(logit - m) : 0.f;
  float s = wave_sum(e);
  float coef = e / s;
  const float* tb = t + (size_t)(b * H + h) * (V * 64);
  float acc = 0.f;
  for (int k = 0; k < dvv; ++k) {
    float c = __shfl(coef, k);
    int w = __shfl(wk, k);
    acc += c * tb[w * 64 + lane];
  }
  __shared__ float hsum[4][64];
  __shared__ float nxts[64], encs[64];
  hsum[h][lane] = acc;
  __syncthreads();
  if (tid < 64) {
    float s4 = hsum[0][tid] + hsum[1][tid] + hsum[2][tid] + hsum[3][tid];
    nxts[tid] = fmaxf(0.25f * s4, 0.f);
    encs[tid] = enc_in[bv * 64 + tid];
  }
  __syncthreads();
  float part = 0.f;
  for (int f = h * 16; f < h * 16 + 16; ++f)
    part += nxts[f] * gate_w[f * 64 + lane] + encs[f] * gate_u[f * 64 + lane];
  __syncthreads();
  hsum[h][lane] = part;
  __syncthreads();
  if (tid < 64) {
    float zs = hsum[0][tid] + hsum[1][tid] + hsum[2][tid] + hsum[3][tid] + gate_b[tid];
    float z = 1.f / (1.f + __expf(-zs));
    enc_out[bv * 64 + tid] = z * nxts[tid] + (1.f - z) * encs[tid];
  }
}

// ---- decoder hidden (linear) + dual variable dv, 8 nodes/block ----
#define DNV 8
__global__ void dec_dual_kernel(const float* __restrict__ enc, const float* __restrict__ dw1,
                                const float* __restrict__ db1, const float* __restrict__ uw1,
                                const float* __restrict__ ub1, const float* __restrict__ uw2,
                                const float* __restrict__ ub2, float* __restrict__ hid,
                                float* __restrict__ dv) {
  int bv0 = blockIdx.x * DNV;
  int j = threadIdx.x;  // 64
  __shared__ float es[DNV][64];
#pragma unroll
  for (int n = 0; n < DNV; ++n) es[n][j] = enc[(bv0 + n) * 64 + j];
  __syncthreads();
  float hj[DNV], uj[DNV];
#pragma unroll
  for (int n = 0; n < DNV; ++n) { hj[n] = db1[j]; uj[n] = ub1[j]; }
  for (int f = 0; f < 64; ++f) {
    float a = dw1[f * 64 + j], c = uw1[f * 64 + j];
#pragma unroll
    for (int n = 0; n < DNV; ++n) {
      hj[n] += es[n][f] * a;
      uj[n] += es[n][f] * c;
    }
  }
  float w2v = uw2[j];
#pragma unroll
  for (int n = 0; n < DNV; ++n) {
    hid[(bv0 + n) * 64 + j] = hj[n];  // NO relu: decoder is linear
    float s = wave_sum(uj[n] * w2v);
    if (j == 0) dv[bv0 + n] = s + ub2[0];
  }
}

__global__ void transpose_w2(const float* __restrict__ w2, float* __restrict__ w2t) {
  int w = blockIdx.x, j = threadIdx.x;
  w2t[w * 64 + j] = w2[j * V + w];
}

// ---- flow weights: softmax over out-edges of pred^2; also row sum of fw^2 ----
__global__ void fw_kernel(const float* __restrict__ hid, const float* __restrict__ w2t,
                          const float* __restrict__ b2, const int* __restrict__ nbr,
                          const int* __restrict__ deg, float* __restrict__ fw,
                          float* __restrict__ rssq) {
  int bv = blockIdx.x;
  int v = bv & 1023;
  int lane = threadIdx.x;  // 64
  float hj = hid[bv * 64 + lane];
  int dvv = deg[v];
  float myp = -1e30f;
  for (int k = 0; k < dvv; ++k) {
    int w = nbr[v * CAP + k];  // wave-uniform
    float d = wave_sum(hj * w2t[w * 64 + lane]);
    float pp = d + b2[w];
    pp = pp * pp;
    if (lane == k) myp = pp;
  }
  float m = wave_max(myp);
  float e = (lane < dvv) ? __expf(myp - m) : 0.f;
  float s = wave_sum(e);
  float coef = e / s;
  fw[bv * CAP + lane] = coef;  // zero-padded beyond deg
  float r = wave_sum(coef * coef);
  if (lane == 0) rssq[bv] = r;
}

// ---- flow iterations entirely in LDS (edge data staged once) + dual cost ----
__global__ __launch_bounds__(1024) void flow_dual_kernel(
    const float* __restrict__ fw, const float* __restrict__ rssq,
    const unsigned short* __restrict__ c_src, const int* __restrict__ c_fwi,
    const int* __restrict__ in_off, const float* __restrict__ dv,
    const float* __restrict__ demands, const int* __restrict__ nbr_out,
    const int* __restrict__ deg_out, float* __restrict__ partial) {
  int b = blockIdx.x;
  int v = threadIdx.x;  // 1024
  __shared__ float lfw[MAXNNZ];            // 80 KB
  __shared__ unsigned short lsrc[MAXNNZ];  // 40 KB
  __shared__ float oA[V], oB[V];           // 8 KB
  __shared__ float dvs[V];                 // 4 KB
  __shared__ float red[16];
  int nnz = in_off[V];
  if (nnz > MAXNNZ) nnz = MAXNNZ;
  const float* fwb = fw + (size_t)b * V * CAP;
  for (int e = v; e < nnz; e += V) {
    lfw[e] = fwb[c_fwi[e]];
    lsrc[e] = c_src[e];
  }
  float dem = demands[b * V + v];
  dvs[v] = dv[b * V + v];
  int o0 = in_off[v], o1 = in_off[v + 1];
  if (o1 > nnz) o1 = nnz;
  if (o0 > nnz) o0 = nnz;
  oA[v] = fmaxf(-dem, 0.f);  // o_1 = relu(-demand)
  __syncthreads();
  float* cur = oA;
  float* nxt = oB;
  for (int it = 0; it < 9; ++it) {
    float inflow = 0.f;
    for (int e = o0; e < o1; ++e) inflow += lfw[e] * cur[lsrc[e]];
    nxt[v] = fmaxf(inflow - dem, 0.f);
    __syncthreads();
    float* tmp = cur; cur = nxt; nxt = tmp;
  }
  float o10 = cur[v];
  float local = o10 * o10 * rssq[b * V + v];  // flow_cost contribution
  // dual: loss_b = flow_cost + 0.25*sum_edges relu(dv_v - dv_w)^2 + sum_v dv_v*dem_v
  float dvv = dvs[v];
  int dout = deg_out[v];
  float acc = 0.f;
  for (int k = 0; k < dout; ++k) {
    float diff = dvv - dvs[nbr_out[v * CAP + k]];
    if (diff > 0.f) acc += diff * diff;
  }
  local += 0.25f * acc + dvv * dem;
  // block reduction: wave shuffle then cross-wave
  local = wave_sum(local);
  if ((v & 63) == 0) red[v >> 6] = local;
  __syncthreads();
  if (v < 16) {
    float r = red[v];
    for (int o = 8; o > 0; o >>= 1) r += __shfl_xor(r, o, 16);
    if (v == 0) partial[b] = r;
  }
}

__global__ void final_kernel(const float* __restrict__ partial, float* __restrict__ out) {
  if (threadIdx.x == 0) {
    float s = 0.f;
    for (int b = 0; b < B; ++b) s += partial[b];
    out[0] = s * (1.0f / B);
  }
}

extern "C" void kernel_launch(void* const* d_in, const int* in_sizes, int n_in,
                              void* d_out, int out_size, void* d_ws, size_t ws_size,
                              hipStream_t stream) {
  const float* demands = (const float*)d_in[0];
  const float* emb     = (const float*)d_in[1];
  const float* adj     = (const float*)d_in[2];
  const float* enc_w1  = (const float*)d_in[3];
  const float* enc_b1  = (const float*)d_in[4];
  const float* enc_w2  = (const float*)d_in[5];
  const float* enc_b2  = (const float*)d_in[6];
  const float* gat_w   = (const float*)d_in[7];
  const float* gat_a1  = (const float*)d_in[8];
  const float* gat_a2  = (const float*)d_in[9];
  const float* gate_w  = (const float*)d_in[10];
  const float* gate_u  = (const float*)d_in[11];
  const float* gate_b  = (const float*)d_in[12];
  const float* dec_w1  = (const float*)d_in[13];
  const float* dec_b1  = (const float*)d_in[14];
  const float* dec_w2  = (const float*)d_in[15];
  const float* dec_b2  = (const float*)d_in[16];
  const float* dual_w1 = (const float*)d_in[17];
  const float* dual_b1 = (const float*)d_in[18];
  const float* dual_w2 = (const float*)d_in[19];
  const float* dual_b2 = (const float*)d_in[20];

  char* p = (char*)d_ws;
  auto alloc = [&](size_t n) { void* r = (void*)p; p += (n + 255) & ~(size_t)255; return r; };
  int* nbr_out   = (int*)alloc((size_t)V * CAP * 4);
  int* deg_out   = (int*)alloc((size_t)V * 4);
  int* in_src    = (int*)alloc((size_t)V * CAP * 4);
  int* in_fwidx  = (int*)alloc((size_t)V * CAP * 4);
  int* deg_in    = (int*)alloc((size_t)V * 4);
  int* in_off    = (int*)alloc((size_t)(V + 1) * 4);
  unsigned short* c_src = (unsigned short*)alloc((size_t)V * CAP * 2);
  int* c_fwi     = (int*)alloc((size_t)V * CAP * 4);
  float* w2t     = (float*)alloc((size_t)HIDN * V * 4);
  float* encA    = (float*)alloc((size_t)B * V * 64 * 4);
  float* encB    = (float*)alloc((size_t)B * V * 64 * 4);
  float* t       = (float*)alloc((size_t)B * H * V * 64 * 4);
  float* s_self  = (float*)alloc((size_t)B * H * V * 4);
  float* s_nbr   = (float*)alloc((size_t)B * H * V * 4);
  float* hid     = (float*)alloc((size_t)B * V * 64 * 4);
  float* dv      = (float*)alloc((size_t)B * V * 4);
  float* fw      = (float*)alloc((size_t)B * V * CAP * 4);
  float* rssq    = (float*)alloc((size_t)B * V * 4);
  float* partial = (float*)alloc((size_t)B * 4);

  build_csr<<<V, 64, 0, stream>>>(adj, nbr_out, deg_out);
  build_csc<<<V, 64, 0, stream>>>(adj, nbr_out, deg_out, in_src, in_fwidx, deg_in);
  scan_kernel<<<1, V, 0, stream>>>(deg_in, in_off);
  compact_csc<<<V, 64, 0, stream>>>(in_src, in_fwidx, deg_in, in_off, c_src, c_fwi);
  enc_kernel<<<B * V / ENV, 64, 0, stream>>>(demands, emb, enc_w1, enc_b1, enc_w2, enc_b2, encA);
  float* cur = encA;
  float* nxt = encB;
  for (int l = 0; l < 2; ++l) {
    t_kernel<<<B * V / TNV, 256, 0, stream>>>(cur, gat_w, gat_a1, gat_a2, t, s_self, s_nbr);
    gat_kernel<<<B * V, 256, 0, stream>>>(cur, t, s_self, s_nbr, nbr_out, deg_out,
                                          gate_w, gate_u, gate_b, nxt);
    float* tmp = cur; cur = nxt; nxt = tmp;
  }
  transpose_w2<<<V, 64, 0, stream>>>(dec_w2, w2t);
  dec_dual_kernel<<<B * V / DNV, 64, 0, stream>>>(cur, dec_w1, dec_b1, dual_w1, dual_b1,
                                                  dual_w2, dual_b2, hid, dv);
  fw_kernel<<<B * V, 64, 0, stream>>>(hid, w2t, dec_b2, nbr_out, deg_out, fw, rssq);
  flow_dual_kernel<<<B, 1024, 0, stream>>>(fw, rssq, c_src, c_fwi, in_off, dv, demands,
                                           nbr_out, deg_out, partial);
  final_kernel<<<1, 64, 0, stream>>>(partial, (float*)d_out);
}